// Round 6
// baseline (1582.505 us; speedup 1.0000x reference)
//
#include <hip/hip_runtime.h>

// 2-layer stacked LSTM: B=256, T=2048, H=64, layer2 hidden=1.
// One block per batch element (256 blocks), 320 threads (5 waves).
//
// Round-5 post-mortem: all previous variants were LDS-DELIVERY-BOUND: every
// MAC's h-operand came from LDS per-lane (64 KB/CU/step = ~600+ cyc of DS
// pipe), invariant across rounds 1-5 (~1100-1230 us each). Fix: h1 never
// touches LDS. Every wave redundantly computes the c1/h1 update (lane u =
// unit u) from a tiny activated-gate exchange (a_lds, 5 ds ops/wave/step),
// then broadcasts h via v_readlane -> SGPR -> v_fmac(v,s,v). LDS traffic
// drops ~30x; the dot runs on the VALU pipe.
//
// Waves 0-3: gate w for all 64 units (lane l = unit l, col = w*64+l).
//   Activation per wave is uniform (w==1 tanh, w==2 sig(z+1), else sig).
// Wave 4: layer 2, 2-stage pipeline (stage A: butterfly dot for t-1;
//   stage B: recurrent c2/h2 update for t-2), h2 staged to out_lds (no
//   global store in the loop -> no vmcnt drain at the barrier).
// ONE __syncthreads per step.
constexpr int kT = 2048;
constexpr int kB = 256;
constexpr int kH = 64;
constexpr int kThreads = 320;

__device__ __forceinline__ float fast_sig(float x) {
    return __builtin_amdgcn_rcpf(1.0f + __expf(-x));
}
__device__ __forceinline__ float fast_tanh(float x) {
    float t = __expf(2.0f * x);
    return 1.0f - 2.0f * __builtin_amdgcn_rcpf(t + 1.0f);
}
__device__ __forceinline__ float rlane(float v, int k) {
    // wave-uniform broadcast of lane k through an SGPR (VALU pipe, not DS)
    return __int_as_float(__builtin_amdgcn_readlane(__float_as_int(v), k));
}

__global__ __launch_bounds__(kThreads) void lstm2_kernel(
    const float* __restrict__ x, const float* __restrict__ W1,
    const float* __restrict__ b1, const float* __restrict__ W2,
    const float* __restrict__ b2, float* __restrict__ out)
{
    __shared__ float x_lds[kT];            // input row
    __shared__ float a_lds[2][4 * kH];     // double-buffered activated gates
    __shared__ float out_lds[kT];          // staged outputs

    const int tid = threadIdx.x;
    const int b = blockIdx.x;
    const float* xg = x + (size_t)b * kT;
    float* outg = out + (size_t)b * kT;

    for (int i = tid; i < kT; i += kThreads) x_lds[i] = xg[i];

    const int w = tid >> 6;   // wave id 0..4
    const int l = tid & 63;   // lane = unit

    // ---- layer-1 column weights (waves 0-3): 64 + 2 regs ----
    float wv[kH];
    float w0 = 0.0f, b1g = 0.0f;
    // ---- replicated layer-1 cell state (ALL waves, lane l = unit l) ----
    float c1 = 0.0f;

    // ---- layer-2 state (wave 4) ----
    float w2i = 0, w2j = 0, w2f = 0, w2o = 0;
    float4 w2t = {0, 0, 0, 0}, b2v = {0, 0, 0, 0};
    float c2 = 0.0f, h2 = 0.0f;
    float zi_s = 0, zj_s = 0, zf_s = 0, zo_s = 0;

    if (w < 4) {
        const int col = w * kH + l;        // gate-major column
        w0 = W1[col];
        b1g = b1[col];
        #pragma unroll
        for (int k = 0; k < kH; ++k) wv[k] = W1[(k + 1) * 256 + col];
    } else {
        w2i = W2[l * 4 + 0];
        w2j = W2[l * 4 + 1];
        w2f = W2[l * 4 + 2];
        w2o = W2[l * 4 + 3];
        w2t = ((const float4*)W2)[kH];     // W2 row 64: h2 recurrent weights
        b2v = ((const float4*)b2)[0];
    }
    __syncthreads();

    for (int t = 0; t < kT; ++t) {
        const int pb = (t - 1) & 1;        // prev a-buffer (valid for t>0)
        const int cb = t & 1;              // buffer written this step
        // ---- redundant c1/h1 update (all 5 waves): h1(t-1) in lane l ----
        float h_new = 0.0f;
        if (t > 0) {
            const float ai = a_lds[pb][l];
            const float aj = a_lds[pb][kH + l];
            const float af = a_lds[pb][2 * kH + l];
            const float ao = a_lds[pb][3 * kH + l];
            c1 = fmaf(af, c1, ai * aj);
            h_new = ao * fast_tanh(c1);
        }
        if (w < 4) {
            // ---- layer-1 dot: h broadcast via readlane (SGPR), no LDS ----
            float z0 = fmaf(x_lds[t], w0, b1g), z1 = 0.f, z2 = 0.f, z3 = 0.f;
            #pragma unroll
            for (int k = 0; k < 16; ++k) {
                z0 = fmaf(rlane(h_new, 4 * k + 0), wv[4 * k + 0], z0);
                z1 = fmaf(rlane(h_new, 4 * k + 1), wv[4 * k + 1], z1);
                z2 = fmaf(rlane(h_new, 4 * k + 2), wv[4 * k + 2], z2);
                z3 = fmaf(rlane(h_new, 4 * k + 3), wv[4 * k + 3], z3);
            }
            const float z = (z0 + z1) + (z2 + z3);
            float a;
            if (w == 1)      a = fast_tanh(z);        // wave-uniform choice
            else if (w == 2) a = fast_sig(z + 1.0f);  // forget bias
            else             a = fast_sig(z);
            a_lds[cb][w * kH + l] = a;
        } else {
            // ---- stage B: c2/h2 update for step t-2 (staged z) ----
            if (t >= 2) {
                const float zi = zi_s + h2 * w2t.x;
                const float zj = zj_s + h2 * w2t.y;
                const float zf = zf_s + h2 * w2t.z;
                const float zo = zo_s + h2 * w2t.w;
                c2 = fast_sig(zf + 1.0f) * c2 + fast_sig(zi) * fast_tanh(zj);
                h2 = fast_sig(zo) * fast_tanh(c2);
                if (l == 0) out_lds[t - 2] = h2;
            }
            // ---- stage A: layer-2 dot for step t-1 (uses h_new) ----
            if (t >= 1) {
                float p0 = h_new * w2i;
                float p1 = h_new * w2j;
                float p2 = h_new * w2f;
                float p3 = h_new * w2o;
                #pragma unroll
                for (int m = 1; m < 64; m <<= 1) {
                    p0 += __shfl_xor(p0, m);
                    p1 += __shfl_xor(p1, m);
                    p2 += __shfl_xor(p2, m);
                    p3 += __shfl_xor(p3, m);
                }
                zi_s = p0 + b2v.x;
                zj_s = p1 + b2v.y;
                zf_s = p2 + b2v.z;
                zo_s = p3 + b2v.w;
            }
        }
        __syncthreads();
    }

    // ---- epilogue (wave 4): finish steps T-2 and T-1 ----
    if (w == 4) {
        // final redundant update: h1(T-1) from a(T-1)
        const int pb = (kT - 1) & 1;
        const float ai = a_lds[pb][l];
        const float aj = a_lds[pb][kH + l];
        const float af = a_lds[pb][2 * kH + l];
        const float ao = a_lds[pb][3 * kH + l];
        c1 = fmaf(af, c1, ai * aj);
        const float h_new = ao * fast_tanh(c1);
        {   // stage B for T-2
            const float zi = zi_s + h2 * w2t.x;
            const float zj = zj_s + h2 * w2t.y;
            const float zf = zf_s + h2 * w2t.z;
            const float zo = zo_s + h2 * w2t.w;
            c2 = fast_sig(zf + 1.0f) * c2 + fast_sig(zi) * fast_tanh(zj);
            h2 = fast_sig(zo) * fast_tanh(c2);
            if (l == 0) out_lds[kT - 2] = h2;
        }
        {   // stage A + B for T-1
            float p0 = h_new * w2i;
            float p1 = h_new * w2j;
            float p2 = h_new * w2f;
            float p3 = h_new * w2o;
            #pragma unroll
            for (int m = 1; m < 64; m <<= 1) {
                p0 += __shfl_xor(p0, m);
                p1 += __shfl_xor(p1, m);
                p2 += __shfl_xor(p2, m);
                p3 += __shfl_xor(p3, m);
            }
            const float zi = p0 + b2v.x + h2 * w2t.x;
            const float zj = p1 + b2v.y + h2 * w2t.y;
            const float zf = p2 + b2v.z + h2 * w2t.z;
            const float zo = p3 + b2v.w + h2 * w2t.w;
            c2 = fast_sig(zf + 1.0f) * c2 + fast_sig(zi) * fast_tanh(zj);
            h2 = fast_sig(zo) * fast_tanh(c2);
            if (l == 0) out_lds[kT - 1] = h2;
        }
    }
    __syncthreads();
    // ---- single coalesced output flush ----
    for (int i = tid; i < kT; i += kThreads) outg[i] = out_lds[i];
}

extern "C" void kernel_launch(void* const* d_in, const int* in_sizes, int n_in,
                              void* d_out, int out_size, void* d_ws, size_t ws_size,
                              hipStream_t stream) {
    const float* x  = (const float*)d_in[0];
    const float* W1 = (const float*)d_in[1];
    const float* b1 = (const float*)d_in[2];
    const float* W2 = (const float*)d_in[3];
    const float* b2 = (const float*)d_in[4];
    float* out = (float*)d_out;
    lstm2_kernel<<<kB, kThreads, 0, stream>>>(x, W1, b1, W2, b2, out);
}

// Round 7
// 1532.851 us; speedup vs baseline: 1.0324x; 1.0324x over previous
//
#include <hip/hip_runtime.h>

// 2-layer stacked LSTM: B=256, T=2048, H=64, layer2 hidden=1.
// One block per batch element (256 blocks), 512 threads (8 waves).
//
// Unified model from rounds 1-6:
//  (a) h-from-LDS designs are DS-delivery-bound: 64 KB/step @ ~100 B/cyc
//      => ~600 cyc/step floor (r1-r5, all ~1100-1230 us).
//  (b) 64 weights/lane never go register-resident (allocator clamps at the
//      default 64-VGPR budget; waves_per_eu(1) did not bite) => per-step
//      scratch/L2 weight re-fetch, ~1 ms floor (r1-r4, r6).
//  Escape: <=32 weights/lane (resident by construction, proven in r5:
//  VGPR=48) AND h broadcast via v_readlane->SGPR->v_fmac (VALU pipe) AND
//  wave-uniform readlane indices.
//
// Mapping: wave v: gate gv=v>>1, row-half hv=v&1 (wave-uniform => uniform
// readlane indices). Lane l = unit l. Wave v covers rows 32hv..32hv+31 of
// gate gv's 64 columns: 32 weights/lane. Every wave redundantly updates
// c1/h1 (lane=unit) from a_lds (stride-5 padded gate exchange, conflict-
// free). Wave-pair partials combine via z_lds (second barrier); hv==0 waves
// do combine+activate. Layer 2 rides wave 1 (idle in phase 2 otherwise):
// stage A split across the two phases (butterfly latency hides under
// phase 1), stage B 2-step-behind pipeline. Outputs staged in out_lds,
// one coalesced flush at the end.
constexpr int kT = 2048;
constexpr int kB = 256;
constexpr int kH = 64;
constexpr int kThreads = 512;

__device__ __forceinline__ float fast_sig(float x) {
    return __builtin_amdgcn_rcpf(1.0f + __expf(-x));
}
__device__ __forceinline__ float fast_tanh(float x) {
    float t = __expf(2.0f * x);
    return 1.0f - 2.0f * __builtin_amdgcn_rcpf(t + 1.0f);
}
__device__ __forceinline__ float rlane(float v, int k) {
    // wave-uniform broadcast of lane k through an SGPR (VALU, not DS pipe)
    return __int_as_float(__builtin_amdgcn_readlane(__float_as_int(v), k));
}

__global__ __launch_bounds__(kThreads) void lstm2_kernel(
    const float* __restrict__ x, const float* __restrict__ W1,
    const float* __restrict__ b1, const float* __restrict__ W2,
    const float* __restrict__ b2, float* __restrict__ out)
{
    __shared__ float x_lds[kT];        // input row
    __shared__ float out_lds[kT];      // staged outputs
    __shared__ float z_lds[2][256];    // per-half partial dots
    __shared__ float a_lds[5 * kH];    // activated gates, unit*5+gate (pad 5)
    __shared__ float w2g_lds[4 * kH];  // W2 transposed: [gate][unit]

    const int tid = threadIdx.x;
    const int b = blockIdx.x;
    const float* xg = x + (size_t)b * kT;
    float* outg = out + (size_t)b * kT;

    for (int i = tid; i < kT; i += kThreads) x_lds[i] = xg[i];
    if (tid < 256) w2g_lds[(tid & 3) * kH + (tid >> 2)] = W2[tid];

    const int v  = tid >> 6;     // wave 0..7
    const int l  = tid & 63;     // lane = unit
    const int gv = v >> 1;       // gate 0..3
    const int hv = v & 1;        // row half (wave-uniform)
    const int col = gv * kH + l; // gate-major column

    // ---- 32 register-resident weights: rows 32hv+1 .. 32hv+32 of col ----
    float wq[32];
    #pragma unroll
    for (int q = 0; q < 32; ++q) wq[q] = W1[(hv * 32 + q + 1) * 256 + col];
    const int rbase = __builtin_amdgcn_readfirstlane(hv * 32);

    float w0 = 0.f, b1g = 0.f;             // combine-wave extras (hv==0)
    if (hv == 0) { w0 = W1[col]; b1g = b1[col]; }

    float c1 = 0.f, h_new = 0.f;           // replicated per wave, lane=unit

    // ---- layer-2 state (wave 1) ----
    float4 w2t = {0, 0, 0, 0}, b2v = {0, 0, 0, 0};
    float c2 = 0.f, h2 = 0.f;
    float zi_s = 0, zj_s = 0, zf_s = 0, zo_s = 0;   // staged pre-activations
    float p0 = 0, p1 = 0, p2 = 0, p3 = 0;           // half-reduced partials
    if (v == 1) {
        w2t = ((const float4*)W2)[kH];     // W2 row 64: h2 recurrent weights
        b2v = ((const float4*)b2)[0];
    }
    __syncthreads();

    for (int t = 0; t < kT; ++t) {
        // ================= phase 1 =================
        if (t > 0) {   // redundant c1/h1 update from activated gates
            const float ai = a_lds[5 * l + 0];
            const float aj = a_lds[5 * l + 1];
            const float af = a_lds[5 * l + 2];
            const float ao = a_lds[5 * l + 3];
            c1 = fmaf(af, c1, ai * aj);
            h_new = ao * fast_tanh(c1);
        }
        // partial dot: h broadcast via readlane (uniform indices), no DS
        {
            float z0 = 0.f, z1 = 0.f, z2 = 0.f, z3 = 0.f;
            #pragma unroll
            for (int q = 0; q < 8; ++q) {
                z0 = fmaf(rlane(h_new, rbase + 4 * q + 0), wq[4 * q + 0], z0);
                z1 = fmaf(rlane(h_new, rbase + 4 * q + 1), wq[4 * q + 1], z1);
                z2 = fmaf(rlane(h_new, rbase + 4 * q + 2), wq[4 * q + 2], z2);
                z3 = fmaf(rlane(h_new, rbase + 4 * q + 3), wq[4 * q + 3], z3);
            }
            z_lds[hv][col] = (z0 + z1) + (z2 + z3);
        }
        if (v == 1 && t >= 1) {
            // layer-2 stage A, first half: products + 3 butterfly levels
            const float w2i = w2g_lds[l];
            const float w2j = w2g_lds[kH + l];
            const float w2f = w2g_lds[2 * kH + l];
            const float w2o = w2g_lds[3 * kH + l];
            p0 = h_new * w2i; p1 = h_new * w2j;
            p2 = h_new * w2f; p3 = h_new * w2o;
            #pragma unroll
            for (int m = 1; m <= 4; m <<= 1) {
                p0 += __shfl_xor(p0, m);
                p1 += __shfl_xor(p1, m);
                p2 += __shfl_xor(p2, m);
                p3 += __shfl_xor(p3, m);
            }
        }
        __syncthreads();   // barrier B: partials published
        // ================= phase 2 =================
        if (v == 1) {
            if (t >= 2) {  // stage B: recurrent c2/h2 for step t-2
                const float zi = zi_s + h2 * w2t.x;
                const float zj = zj_s + h2 * w2t.y;
                const float zf = zf_s + h2 * w2t.z;
                const float zo = zo_s + h2 * w2t.w;
                c2 = fast_sig(zf + 1.0f) * c2 + fast_sig(zi) * fast_tanh(zj);
                h2 = fast_sig(zo) * fast_tanh(c2);
                if (l == 0) out_lds[t - 2] = h2;
            }
            if (t >= 1) {  // stage A, second half: finish butterfly + bias
                #pragma unroll
                for (int m = 8; m <= 32; m <<= 1) {
                    p0 += __shfl_xor(p0, m);
                    p1 += __shfl_xor(p1, m);
                    p2 += __shfl_xor(p2, m);
                    p3 += __shfl_xor(p3, m);
                }
                zi_s = p0 + b2v.x;
                zj_s = p1 + b2v.y;
                zf_s = p2 + b2v.z;
                zo_s = p3 + b2v.w;
            }
        } else if (hv == 0) {
            // combine halves + x-term + bias, activate, publish gate
            const float zs = z_lds[0][col] + z_lds[1][col]
                           + fmaf(x_lds[t], w0, b1g);
            float a;
            if (gv == 1)      a = fast_tanh(zs);
            else if (gv == 2) a = fast_sig(zs + 1.0f);   // forget bias
            else              a = fast_sig(zs);
            a_lds[5 * l + gv] = a;
        }
        __syncthreads();   // barrier A: gates published for next step
    }

    // ---- epilogue (wave 1): finish steps T-2 and T-1 ----
    if (v == 1) {
        // final redundant h1 update from a(T-1)
        const float ai = a_lds[5 * l + 0];
        const float aj = a_lds[5 * l + 1];
        const float af = a_lds[5 * l + 2];
        const float ao = a_lds[5 * l + 3];
        c1 = fmaf(af, c1, ai * aj);
        h_new = ao * fast_tanh(c1);
        {   // stage B for T-2 (z staged in last loop iteration)
            const float zi = zi_s + h2 * w2t.x;
            const float zj = zj_s + h2 * w2t.y;
            const float zf = zf_s + h2 * w2t.z;
            const float zo = zo_s + h2 * w2t.w;
            c2 = fast_sig(zf + 1.0f) * c2 + fast_sig(zi) * fast_tanh(zj);
            h2 = fast_sig(zo) * fast_tanh(c2);
            if (l == 0) out_lds[kT - 2] = h2;
        }
        {   // stage A + B for T-1
            const float w2i = w2g_lds[l];
            const float w2j = w2g_lds[kH + l];
            const float w2f = w2g_lds[2 * kH + l];
            const float w2o = w2g_lds[3 * kH + l];
            p0 = h_new * w2i; p1 = h_new * w2j;
            p2 = h_new * w2f; p3 = h_new * w2o;
            #pragma unroll
            for (int m = 1; m < 64; m <<= 1) {
                p0 += __shfl_xor(p0, m);
                p1 += __shfl_xor(p1, m);
                p2 += __shfl_xor(p2, m);
                p3 += __shfl_xor(p3, m);
            }
            const float zi = p0 + b2v.x + h2 * w2t.x;
            const float zj = p1 + b2v.y + h2 * w2t.y;
            const float zf = p2 + b2v.z + h2 * w2t.z;
            const float zo = p3 + b2v.w + h2 * w2t.w;
            c2 = fast_sig(zf + 1.0f) * c2 + fast_sig(zi) * fast_tanh(zj);
            h2 = fast_sig(zo) * fast_tanh(c2);
            if (l == 0) out_lds[kT - 1] = h2;
        }
    }
    __syncthreads();
    // ---- single coalesced output flush ----
    for (int i = tid; i < kT; i += kThreads) outg[i] = out_lds[i];
}

extern "C" void kernel_launch(void* const* d_in, const int* in_sizes, int n_in,
                              void* d_out, int out_size, void* d_ws, size_t ws_size,
                              hipStream_t stream) {
    const float* x  = (const float*)d_in[0];
    const float* W1 = (const float*)d_in[1];
    const float* b1 = (const float*)d_in[2];
    const float* W2 = (const float*)d_in[3];
    const float* b2 = (const float*)d_in[4];
    float* out = (float*)d_out;
    lstm2_kernel<<<kB, kThreads, 0, stream>>>(x, W1, b1, W2, b2, out);
}